// Round 6
// baseline (443.955 us; speedup 1.0000x reference)
//
#include <hip/hip_runtime.h>
#include <math.h>

#define BB 8
#define TT 128
#define U1 65
#define UU 64
#define VV 1024
#define CSTR 130            // comb row stride (pairs)
#define COMB_N 8456         // 65*130 pairs + pad (prefetch overrun headroom)
#define NPROD (BB * TT * U1 / 4)   // 16640 producer blocks
#define BLK_PER_B (TT * U1 / 4)    // 2080 producer blocks per batch
#define NEGINF -1e30f
#define LOG2E 1.4426950408889634f
#define LN2   0.6931471805599453f

// shfl_up by 1 via DPP wave_shr:1 (HW-verified rounds 2-5)
__device__ __forceinline__ float shfl_up1(float x) {
  return __int_as_float(__builtin_amdgcn_update_dpp(
      0, __float_as_int(x), 0x138, 0xf, 0xf, false));
}

// log-add-exp in log2 domain: native v_exp_f32 / v_log_f32
__device__ __forceinline__ float lae2(float a, float b) {
  const float mx = fmaxf(a, b);
  const float nd = fminf(a - b, b - a);     // -|a-b|
  return mx + log2f(1.f + exp2f(nd));
}

// ---------------- single fused kernel: lse producers + DP consumers ----------
// blocks [0, NPROD): one wave per logits row -> lse -> comb stores -> signal.
// blocks [NPROD, NPROD+BB): spin on cnt[b], then anti-diagonal DP from global
// (no __shared__ anywhere: keeps producer occupancy at the VGPR limit).
__global__ __launch_bounds__(256) void rnnt_fused(
    const float* __restrict__ logits, const int* __restrict__ y,
    const int* __restrict__ logit_lens, const int* __restrict__ y_lens,
    float* __restrict__ comb, float* __restrict__ losses,
    int* __restrict__ cnt, int* __restrict__ done, float* __restrict__ out) {
  const int tid = threadIdx.x;

  if (blockIdx.x < NPROD) {
    // ======================= producer: lse + comb emit =======================
    const int wave = tid >> 6;
    const int lane = tid & 63;
    const int row  = blockIdx.x * 4 + wave;       // 4 rows/block, same b (8320%4==0)
    const int u  = row % U1;
    const int bt = row / U1;
    const int b  = bt / TT;
    const int t  = bt % TT;
    float* cb = comb + (size_t)b * COMB_N * 2;

    // structural padding — t=0 / u=0 waves are never skipped
    if (lane == 0) {
      if (t == 0) cb[2 * (u * CSTR) + 0] = NEGINF;    // comb[u][0].x
      if (u == 0) cb[2 * t + 1]          = NEGINF;    // comb[0][t].y
    }
    const bool active = (t < logit_lens[b]) && (u <= y_lens[b]);
    if (active) {
      const float4* rp = (const float4*)(logits + (size_t)row * VV);
      float4 x0 = rp[lane];
      float4 x1 = rp[lane + 64];
      float4 x2 = rp[lane + 128];
      float4 x3 = rp[lane + 192];

      const bool have_label = (u < UU);
      float lab_logit = 0.f;
      if (have_label && lane == 0)
        lab_logit = logits[(size_t)row * VV + y[b * UU + u]];   // L1 hit

      float m = fmaxf(fmaxf(fmaxf(x0.x, x0.y), fmaxf(x0.z, x0.w)),
                      fmaxf(fmaxf(x1.x, x1.y), fmaxf(x1.z, x1.w)));
      m = fmaxf(m, fmaxf(fmaxf(fmaxf(x2.x, x2.y), fmaxf(x2.z, x2.w)),
                         fmaxf(fmaxf(x3.x, x3.y), fmaxf(x3.z, x3.w))));
#pragma unroll
      for (int s = 32; s >= 1; s >>= 1) m = fmaxf(m, __shfl_xor(m, s));

      float ss = __expf(x0.x-m) + __expf(x0.y-m) + __expf(x0.z-m) + __expf(x0.w-m)
               + __expf(x1.x-m) + __expf(x1.y-m) + __expf(x1.z-m) + __expf(x1.w-m)
               + __expf(x2.x-m) + __expf(x2.y-m) + __expf(x2.z-m) + __expf(x2.w-m)
               + __expf(x3.x-m) + __expf(x3.y-m) + __expf(x3.z-m) + __expf(x3.w-m);
#pragma unroll
      for (int s = 32; s >= 1; s >>= 1) ss += __shfl_xor(ss, s);

      if (lane == 0) {
        const float lse = m + __logf(ss);
        cb[2 * (u * CSTR + t + 1) + 0] = (x0.x - lse) * LOG2E;          // blank
        if (have_label)
          cb[2 * ((u + 1) * CSTR + t) + 1] = (lab_logit - lse) * LOG2E; // label
      }
    }
    __syncthreads();   // all 4 waves' stores issued before the block signals
    if (tid == 0)
      __hip_atomic_fetch_add(&cnt[b], 1, __ATOMIC_RELEASE, __HIP_MEMORY_SCOPE_AGENT);
    return;
  }

  // ========================= consumer: alpha DP ==============================
  const int b = blockIdx.x - NPROD;
  if (tid == 0) {
    while (__hip_atomic_load(&cnt[b], __ATOMIC_RELAXED, __HIP_MEMORY_SCOPE_AGENT)
           < BLK_PER_B)
      __builtin_amdgcn_s_sleep(16);
    __hip_atomic_load(&cnt[b], __ATOMIC_ACQUIRE, __HIP_MEMORY_SCOPE_AGENT); // inv caches
  }
  __syncthreads();
  if (tid >= 64) return;
  const int lane = tid;

  const int tEnd = logit_lens[b] - 1;   // in [63,127]
  const int uEnd = y_lens[b];           // in [32,64]
  const int dT   = tEnd + uEnd;         // >= 95

  const float2* cg   = (const float2*)comb + (size_t)b * COMB_N;
  const float2* cp   = cg + 129 * lane;   // cp[d] = comb[u][d-u]
  const float2* cp64 = cg + 8256;         // cp64[d] = comb[64][d-64] (broadcast)

  float A   = (lane == 0) ? 0.f : NEGINF;
  float A64 = NEGINF;

#define STEP(cc, ee)                                      \
  {                                                       \
    const float aleft = shfl_up1(A);                      \
    const float top   = A + (cc).x;                       \
    const float lft   = aleft + (cc).y;                   \
    const float xt    = A64 + (ee).x;                     \
    const float xl    = A + (ee).y;   /* pre-update A */  \
    A   = lae2(top, lft);                                 \
    A64 = lae2(xt, xl);                                   \
  }

  float2 c0 = cp[1], c1 = cp[2], c2 = cp[3], c3 = cp[4];
  float2 e0 = cp64[1], e1 = cp64[2], e2 = cp64[3], e3 = cp64[4];

  int d = 1;
  for (; d + 3 <= dT; d += 4) {
    const float2 n0 = cp[d + 4], n1 = cp[d + 5], n2 = cp[d + 6], n3 = cp[d + 7];
    const float2 f0 = cp64[d + 4], f1 = cp64[d + 5], f2 = cp64[d + 6], f3 = cp64[d + 7];
    STEP(c0, e0) STEP(c1, e1) STEP(c2, e2) STEP(c3, e3)
    c0 = n0; c1 = n1; c2 = n2; c3 = n3;
    e0 = f0; e1 = f1; e2 = f2; e3 = f3;
  }
  for (; d <= dT; ++d) {
    const float2 c = cp[d], e = cp64[d];
    STEP(c, e)
  }
#undef STEP

  float res = 0.f;
  bool have = false;
  if (uEnd == 64) {
    if (lane == 63) { res = A64 + cg[64 * CSTR + tEnd + 1].x; have = true; }
  } else if (lane == uEnd) {
    res = A + cg[uEnd * CSTR + tEnd + 1].x; have = true;
  }

  if (have) {
    __hip_atomic_store(&losses[b], -res * LN2, __ATOMIC_RELEASE,
                       __HIP_MEMORY_SCOPE_AGENT);
    const int tk = __hip_atomic_fetch_add(done, 1, __ATOMIC_ACQ_REL,
                                          __HIP_MEMORY_SCOPE_AGENT);
    if (tk == BB - 1) {                    // last consumer: deterministic mean
      float s = 0.f;
#pragma unroll
      for (int i = 0; i < BB; ++i)
        s += __hip_atomic_load(&losses[i], __ATOMIC_ACQUIRE,
                               __HIP_MEMORY_SCOPE_AGENT);
      out[0] = s * (1.f / BB);
    }
  }
}

extern "C" void kernel_launch(void* const* d_in, const int* in_sizes, int n_in,
                              void* d_out, int out_size, void* d_ws, size_t ws_size,
                              hipStream_t stream) {
  const float* logits     = (const float*)d_in[0];
  const int*   logit_lens = (const int*)d_in[1];
  const int*   y          = (const int*)d_in[2];
  const int*   y_lens     = (const int*)d_in[3];
  float* out = (float*)d_out;

  float2* comb   = (float2*)d_ws;                       // BB * COMB_N pairs
  float*  losses = (float*)(comb + (size_t)BB * COMB_N);
  int*    cnt    = (int*)(losses + BB);                 // BB counters
  int*    done   = cnt + BB;                            // ticket

  hipMemsetAsync(cnt, 0, (BB + 1) * sizeof(int), stream);  // graph-legal reset
  rnnt_fused<<<NPROD + BB, 256, 0, stream>>>(logits, y, logit_lens, y_lens,
                                             (float*)comb, losses, cnt, done, out);
}

// Round 7
// 59.715 us; speedup vs baseline: 7.4345x; 7.4345x over previous
//
#include <hip/hip_runtime.h>
#include <math.h>

#define BB 8
#define TT 128
#define U1 65
#define UU 64
#define VV 1024
#define CSTR 130            // comb row stride (pairs)
#define COMB_N 8456         // 65*130 pairs + 6 pad (prefetch overrun headroom)
#define RPW 8               // rows per wave
#define RPB 32              // rows per block (4 waves)
#define NBLK (BB * TT * U1 / RPB)   // 2080 blocks: whole grid resident at once
#define NEGINF -1e30f
#define LOG2E 1.4426950408889634f
#define LN2   0.6931471805599453f

// shfl_up by 1 via DPP wave_shr:1 (HW-verified rounds 2-5)
__device__ __forceinline__ float shfl_up1(float x) {
  return __int_as_float(__builtin_amdgcn_update_dpp(
      0, __float_as_int(x), 0x138, 0xf, 0xf, false));
}

// log-add-exp in log2 domain: native v_exp_f32 / v_log_f32
__device__ __forceinline__ float lae2(float a, float b) {
  const float mx = fmaxf(a, b);
  const float nd = fminf(a - b, b - a);     // -|a-b|
  return mx + log2f(1.f + exp2f(nd));
}

// ---------------- Kernel 1: logsumexp + fused comb emit, 8 rows per wave -----
// 2080 blocks x 256 threads: ~8 blocks/CU -> entire grid resident, no dispatch
// churn. Per-row math identical to round 3 (A/B on block count).
__global__ __launch_bounds__(256) void lse_gather(
    const float* __restrict__ logits, const int* __restrict__ y,
    const int* __restrict__ logit_lens, const int* __restrict__ y_lens,
    float* __restrict__ comb) {
  const int wave = threadIdx.x >> 6;
  const int lane = threadIdx.x & 63;
  const int row0 = blockIdx.x * RPB + wave * RPW;
  const int b    = row0 / (TT * U1);            // block-uniform (8320 % 32 == 0)
  const int tlen = logit_lens[b];               // hoisted scalar loads
  const int ulen = y_lens[b];
  float* cb = comb + (size_t)b * COMB_N * 2;

#pragma unroll
  for (int r = 0; r < RPW; ++r) {
    const int row = row0 + r;
    const int u = row % U1;
    const int t = (row / U1) % TT;

    // structural padding — t=0 / u=0 rows always reach here
    if (lane == 0) {
      if (t == 0) cb[2 * (u * CSTR) + 0] = NEGINF;    // comb[u][0].x
      if (u == 0) cb[2 * t + 1]          = NEGINF;    // comb[0][t].y
    }
    if (t >= tlen || u > ulen) continue;              // wave-uniform skip

    const float4* rp = (const float4*)(logits + (size_t)row * VV);
    const float4 x0 = rp[lane];
    const float4 x1 = rp[lane + 64];
    const float4 x2 = rp[lane + 128];
    const float4 x3 = rp[lane + 192];

    const bool have_label = (u < UU);
    float lab_logit = 0.f;
    if (have_label && lane == 0)
      lab_logit = logits[(size_t)row * VV + y[b * UU + u]];   // L1 hit

    float m = fmaxf(fmaxf(fmaxf(x0.x, x0.y), fmaxf(x0.z, x0.w)),
                    fmaxf(fmaxf(x1.x, x1.y), fmaxf(x1.z, x1.w)));
    m = fmaxf(m, fmaxf(fmaxf(fmaxf(x2.x, x2.y), fmaxf(x2.z, x2.w)),
                       fmaxf(fmaxf(x3.x, x3.y), fmaxf(x3.z, x3.w))));
#pragma unroll
    for (int s = 32; s >= 1; s >>= 1) m = fmaxf(m, __shfl_xor(m, s));

    float ss = __expf(x0.x-m) + __expf(x0.y-m) + __expf(x0.z-m) + __expf(x0.w-m)
             + __expf(x1.x-m) + __expf(x1.y-m) + __expf(x1.z-m) + __expf(x1.w-m)
             + __expf(x2.x-m) + __expf(x2.y-m) + __expf(x2.z-m) + __expf(x2.w-m)
             + __expf(x3.x-m) + __expf(x3.y-m) + __expf(x3.z-m) + __expf(x3.w-m);
#pragma unroll
    for (int s = 32; s >= 1; s >>= 1) ss += __shfl_xor(ss, s);

    if (lane == 0) {
      const float lse = m + __logf(ss);
      cb[2 * (u * CSTR + t + 1) + 0] = (x0.x - lse) * LOG2E;          // blank
      if (have_label)
        cb[2 * ((u + 1) * CSTR + t) + 1] = (lab_logit - lse) * LOG2E; // label
    }
  }
}

// ---------------- Kernel 2: anti-diagonal alpha recursion (round-3 proven) ---
__global__ __launch_bounds__(256) void alpha_dp(
    const float2* __restrict__ comb, const int* __restrict__ logit_lens,
    const int* __restrict__ y_lens, float* __restrict__ losses) {
  const int b = blockIdx.x;
  const int tid = threadIdx.x;

  __shared__ __align__(16) float2 cs[COMB_N];
  {
    const float4* g = (const float4*)(comb + (size_t)b * COMB_N);
    float4* s = (float4*)cs;
    for (int i = tid; i < COMB_N / 2; i += 256) s[i] = g[i];
  }
  __syncthreads();
  if (tid >= 64) return;
  const int lane = tid;

  const int tEnd = logit_lens[b] - 1;   // in [63,127]
  const int uEnd = y_lens[b];           // in [32,64]
  const int dT   = tEnd + uEnd;         // >= 95

  const float2* cp   = cs + 129 * lane; // cp[d] = comb[u][d-u]
  const float2* cp64 = cs + 8256;       // cp64[d] = comb[64][d-64] (broadcast)

  float A   = (lane == 0) ? 0.f : NEGINF;
  float A64 = NEGINF;

#define STEP(cc, ee)                                      \
  {                                                       \
    const float aleft = shfl_up1(A);                      \
    const float top   = A + (cc).x;                       \
    const float lft   = aleft + (cc).y;                   \
    const float xt    = A64 + (ee).x;                     \
    const float xl    = A + (ee).y;   /* pre-update A */  \
    A   = lae2(top, lft);                                 \
    A64 = lae2(xt, xl);                                   \
  }

  float2 c0 = cp[1], c1 = cp[2], c2 = cp[3], c3 = cp[4];
  float2 e0 = cp64[1], e1 = cp64[2], e2 = cp64[3], e3 = cp64[4];

  int d = 1;
  for (; d + 3 <= dT; d += 4) {
    const float2 n0 = cp[d + 4], n1 = cp[d + 5], n2 = cp[d + 6], n3 = cp[d + 7];
    const float2 f0 = cp64[d + 4], f1 = cp64[d + 5], f2 = cp64[d + 6], f3 = cp64[d + 7];
    STEP(c0, e0) STEP(c1, e1) STEP(c2, e2) STEP(c3, e3)
    c0 = n0; c1 = n1; c2 = n2; c3 = n3;
    e0 = f0; e1 = f1; e2 = f2; e3 = f3;
  }
  for (; d <= dT; ++d) {
    const float2 c = cp[d], e = cp64[d];
    STEP(c, e)
  }
#undef STEP

  if (uEnd == 64) {
    if (lane == 63) losses[b] = -(A64 + cs[64 * CSTR + tEnd + 1].x) * LN2;
  } else {
    if (lane == uEnd) losses[b] = -(A + cs[uEnd * CSTR + tEnd + 1].x) * LN2;
  }
}

// ---------------- Kernel 3: mean over batch ----------------------------------
__global__ void finalize(const float* __restrict__ losses, float* __restrict__ out) {
  if (threadIdx.x == 0) {
    float s = 0.f;
#pragma unroll
    for (int i = 0; i < BB; ++i) s += losses[i];
    out[0] = s / (float)BB;
  }
}

extern "C" void kernel_launch(void* const* d_in, const int* in_sizes, int n_in,
                              void* d_out, int out_size, void* d_ws, size_t ws_size,
                              hipStream_t stream) {
  const float* logits     = (const float*)d_in[0];
  const int*   logit_lens = (const int*)d_in[1];
  const int*   y          = (const int*)d_in[2];
  const int*   y_lens     = (const int*)d_in[3];
  float* out = (float*)d_out;

  float2* comb   = (float2*)d_ws;                       // BB * COMB_N pairs
  float*  losses = (float*)(comb + (size_t)BB * COMB_N);

  lse_gather<<<NBLK, 256, 0, stream>>>(logits, y, logit_lens, y_lens, (float*)comb);
  alpha_dp<<<BB, 256, 0, stream>>>(comb, logit_lens, y_lens, losses);
  finalize<<<1, 64, 0, stream>>>(losses, out);
}